// Round 7
// baseline (7158.314 us; speedup 1.0000x reference)
//
#include <hip/hip_runtime.h>
#include <hip/hip_bf16.h>
#include <stdint.h>

// LSTM bidirectional 2-layer, T=512 B=64 D=H=512.
// prep(cast+bias+ring-init) -> gemm_xg(L0) -> rec(L0) -> gemm_xg(L1) -> rec(L1).
// R7: single-hop sync on a COMPACT 512KB ring with per-u16 tag-in-data
//   (h in [-1,1] => fp16 bit14 always 0). Orthogonal per-layer tag alphabets:
//   L0 {0000,1111}, L1 {1010,0101}, ring init = neutral 0011 (matches nothing).
// R9: dual-chain (fwd+bwd) per WG, 64 WGs x 512 thr.
// R10: (a) launch_bounds(512,1): R9's 128-VGPR cap made wregA/B (128 regs) im-
//   possible to keep resident -> hidden per-step W reloads. Now ~200 VGPR OK.
//   (b) gate-interleaved MFMA B-layout: wave's 16 cols = 4 gates x 4 h-cols;
//   gate regroup via shfl_xor in-register. Kills accbuf (bank conflicts) and
//   halves barriers (2/iter). Pointwise+xg spread over all 8 waves.
//   (c) split-issue polls: issue B(s) before mfmaA, A(s+1) before mfmaB; check
//   with counted vmcnt(2/4) (never waits own store-acks). Regs pre-cleared to
//   a NEUTRAL tag pattern -> early return can only look stale (recheck), never
//   false-match. Partial 16B writes always leave >=1 neutral dword -> caught.
// R5 carry-over: xg stores/loads non-temporal (268MB read-once stream).

typedef __attribute__((ext_vector_type(8))) _Float16 half8;
typedef __attribute__((ext_vector_type(4))) float f32x4;
typedef __attribute__((ext_vector_type(4))) uint32_t u32x4;
typedef unsigned long long ull;

#define AS(p, v) __hip_atomic_store((p), (v), __ATOMIC_RELAXED, __HIP_MEMORY_SCOPE_AGENT)

#define TAGMASK 0x4000400040004000ULL   // bit14 of halves 0..3
#define TM32    0x40004000u
#define PAT_L1A 0x0000400000004000ULL   // halves 0,2  (L1 parity 0)
#define PAT_L1B 0x4000000040000000ULL   // halves 1,3  (L1 parity 1)
// neutral ring-init pattern: halves 0,1 tagged -> matches no layer expectation
#define PAT_INIT_LO 0x40004000u
#define PAT_INIT_HI 0x00000000u

__device__ __forceinline__ unsigned short f2h(float f) {
    union { _Float16 h; unsigned short u; } c; c.h = (_Float16)f; return c.u;
}
__device__ __forceinline__ float h2f(unsigned short u) {
    union { _Float16 h; unsigned short u; } c; c.u = u; return (float)c.h;
}

// ---------------- prep: casts, bias sums, ring init (neutral pattern) ----------------
__global__ __launch_bounds__(256) void prep_kernel(
    const float* __restrict__ x,
    const float* __restrict__ w0f, const float* __restrict__ w0b,
    const float* __restrict__ w1f, const float* __restrict__ w1b,
    const float* __restrict__ bi0f, const float* __restrict__ bh0f,
    const float* __restrict__ bi0b, const float* __restrict__ bh0b,
    const float* __restrict__ bi1f, const float* __restrict__ bh1f,
    const float* __restrict__ bi1b, const float* __restrict__ bh1b,
    unsigned short* __restrict__ xh,
    unsigned short* __restrict__ wihh,
    float* __restrict__ bias,
    uint32_t* __restrict__ hbufi)          // ring init: 512KB neutral pattern
{
    const long total = 5801984L;   // units of 16B quads
    long stride = (long)gridDim.x * blockDim.x;
    for (long i = (long)blockIdx.x * blockDim.x + threadIdx.x; i < total; i += stride) {
        if (i < 4194304L) {                       // x: fp32 -> fp16 (16.78M elems)
            float4 v = ((const float4*)x)[i];
            ushort4 o; o.x=f2h(v.x); o.y=f2h(v.y); o.z=f2h(v.z); o.w=f2h(v.w);
            ((ushort4*)xh)[i] = o;
        } else if (i < 5767168L) {                // w_ih casts: [w0f][w0b][w1f][w1b]
            long j = i - 4194304L;
            const float* src; long sq;
            if (j < 262144L)       { src = w0f; sq = j;            }
            else if (j < 524288L)  { src = w0b; sq = j - 262144L;  }
            else if (j < 1048576L) { src = w1f; sq = j - 524288L;  }
            else                   { src = w1b; sq = j - 1048576L; }
            float4 v = ((const float4*)src)[sq];
            ushort4 o; o.x=f2h(v.x); o.y=f2h(v.y); o.z=f2h(v.z); o.w=f2h(v.w);
            ((ushort4*)wihh)[j] = o;
        } else if (i < 5769216L) {                // bias sums: b_ih + b_hh, 4 x 2048 fp32
            long j = i - 5767168L;                // 0..2047 quads
            int ld = (int)(j >> 9);
            long cq = j & 511L;
            const float* bi = ld==0?bi0f: ld==1?bi0b: ld==2?bi1f:bi1b;
            const float* bh = ld==0?bh0f: ld==1?bh0b: ld==2?bh1f:bh1b;
            float4 a = ((const float4*)bi)[cq];
            float4 b = ((const float4*)bh)[cq];
            float4 o; o.x=a.x+b.x; o.y=a.y+b.y; o.z=a.z+b.z; o.w=a.w+b.w;
            ((float4*)bias)[ld*512 + cq] = o;
        } else {                                  // ring init: 32768 quads = 512KB
            long j = i - 5769216L;
            uint4 p; p.x=PAT_INIT_LO; p.y=PAT_INIT_HI; p.z=PAT_INIT_LO; p.w=PAT_INIT_HI;
            ((uint4*)hbufi)[j] = p;
        }
    }
}

// ---------------- xg GEMM: xg = A @ W^T, fp16 out, TRANSPOSED layout ----------------
__global__ __launch_bounds__(256) void gemm_xg(
    const unsigned short* __restrict__ A,
    const unsigned short* __restrict__ Wf,
    const unsigned short* __restrict__ Wb,
    unsigned short* __restrict__ xg,
    int Din)
{
    __shared__ __align__(16) unsigned short As[4096];   // 128 rows x 32 k, fp16
    __shared__ __align__(16) unsigned short Bs[4096];
    const int dir = blockIdx.z;
    const unsigned short* W = dir ? Wb : Wf;
    unsigned short* out = xg + (size_t)dir * 32768 * 2048;
    const int bn = blockIdx.x, bm = blockIdx.y;
    const int tid = threadIdx.x;
    const int wave = tid >> 6, lane = tid & 63;
    const int q = lane >> 4, ln = lane & 15;
    const int wm = wave >> 1, wn = wave & 1;

    f32x4 acc[4][4];
#pragma unroll
    for (int a = 0; a < 4; ++a)
#pragma unroll
        for (int b = 0; b < 4; ++b) acc[a][b] = (f32x4){0.f, 0.f, 0.f, 0.f};

    const int kiter = Din >> 5;
    for (int kb = 0; kb < kiter; ++kb) {
        __syncthreads();
#pragma unroll
        for (int i = 0; i < 2; ++i) {
            int off = i*4096 + wave*1024 + lane*16;   // byte offset in 8KB tile
            int row = off >> 6;
            int kel = (off & 63) >> 1;
            const unsigned short* sa = A + (size_t)(bm*128 + row)*Din + kb*32 + kel;
            const unsigned short* sb = W + (size_t)(bn*128 + row)*Din + kb*32 + kel;
            __builtin_amdgcn_global_load_lds(
                (const __attribute__((address_space(1))) uint32_t*)sa,
                (__attribute__((address_space(3))) uint32_t*)((char*)As + i*4096 + wave*1024),
                16, 0, 0);
            __builtin_amdgcn_global_load_lds(
                (const __attribute__((address_space(1))) uint32_t*)sb,
                (__attribute__((address_space(3))) uint32_t*)((char*)Bs + i*4096 + wave*1024),
                16, 0, 0);
        }
        __syncthreads();
        half8 af[4], bf[4];
#pragma unroll
        for (int mt = 0; mt < 4; ++mt)
            af[mt] = *(const half8*)((const char*)As + (wm*64 + mt*16 + ln)*64 + q*16);
#pragma unroll
        for (int nt = 0; nt < 4; ++nt)
            bf[nt] = *(const half8*)((const char*)Bs + (wn*64 + nt*16 + ln)*64 + q*16);
#pragma unroll
        for (int mt = 0; mt < 4; ++mt)
#pragma unroll
            for (int nt = 0; nt < 4; ++nt)
                acc[mt][nt] = __builtin_amdgcn_mfma_f32_16x16x32_f16(af[mt], bf[nt], acc[mt][nt], 0, 0, 0);
    }
    const int tt = bm*2 + wm;
#pragma unroll
    for (int mt = 0; mt < 4; ++mt)
#pragma unroll
        for (int nt = 0; nt < 4; ++nt) {
            int col = bn*128 + wn*64 + nt*16 + ln;
            int gate = col >> 9, colg = col & 511;
            union { unsigned short u[4]; ull v; } p;
#pragma unroll
            for (int r = 0; r < 4; ++r) p.u[r] = f2h(acc[mt][nt][r]);
            __builtin_nontemporal_store(p.v,
                (ull*)(out + (((size_t)tt*4 + gate)*512 + colg)*64 + mt*16 + q*4));
        }
}

// ---------------- recurrent kernel: one layer, BOTH directions per WG ----------------
// 64 WGs x 512 threads (8 waves). WG = (bh batch/16, cg 32 h-cols), both dirs.
// Wave wv owns cols C0+wv*4..+3; its 16 MFMA B-cols = lane ln -> (gate=ln&3,
// col=C0+wv*4+(ln>>2)). W_hh both dirs in REGISTERS (32 half8 = 128 VGPR).
__global__ __launch_bounds__(512, 1) void rec_kernel(
    const unsigned short* __restrict__ xg,    // [dir][t][gate][hcol][brow] fp16, bias-free
    const float* __restrict__ whhf,           // [2048][512] fp32
    const float* __restrict__ whhb,
    const float* __restrict__ bias,           // [2 dir][2048] fp32 (b_ih+b_hh)
    unsigned short* __restrict__ hbuf,        // ring [4 slot][2 dir][64][512] fp16, tagged
    unsigned short* __restrict__ outh,        // layer0: in1 [T][64][1024] fp16
    float* __restrict__ outf,                 // layer1: d_out fp32 [T][64][1024]
    const int layer)
{
    // h staging double-buffered per chain: [chain(2)][parity(2)][16 rows][512 cols] swz
    __shared__ __align__(16) unsigned short h_lds[32768];  // 64KB
    __shared__ __align__(16) unsigned short htile[512];    // 1KB: [wv(8)][16 rows][4 cols]

    const int bx = blockIdx.x;                 // 64 WGs
    const int bh = bx & 3, cg = bx >> 2;
    const int R0 = bh*16, C0 = cg*32;
    const int tid = threadIdx.x;
    const int wv = tid >> 6, lane = tid & 63;
    const int ln = lane & 15, q = lane >> 4;
    const int gate = ln & 3, lc = ln >> 2;
    const int col = C0 + wv*4 + lc;

    const ull pat0 = layer ? PAT_L1A : 0ULL;
    const ull pat1 = layer ? PAT_L1B : TAGMASK;
    const uint32_t ep0 = (uint32_t)(pat0 & 0xffffffffULL);
    const uint32_t ep1 = (uint32_t)(pat1 & 0xffffffffULL);
    // neutral clear dword: tag pair matching NEITHER expectation of this layer
    const uint32_t NC = layer ? 0u : 0x40000000u;

    // ---- W_hh -> registers, both dirs: wreg[kk] = W[gate*512+col][kk*32+q*8 ..+8] ----
    half8 wregA[16], wregB[16];
    {
        const float* srcA = whhf + (size_t)(gate*512 + col)*512 + q*8;
        const float* srcB = whhb + (size_t)(gate*512 + col)*512 + q*8;
#pragma unroll
        for (int kk = 0; kk < 16; ++kk) {
            float4 v0 = *(const float4*)(srcA + kk*32);
            float4 v1 = *(const float4*)(srcA + kk*32 + 4);
            union { unsigned short u[8]; half8 v; } p;
            p.u[0]=f2h(v0.x); p.u[1]=f2h(v0.y); p.u[2]=f2h(v0.z); p.u[3]=f2h(v0.w);
            p.u[4]=f2h(v1.x); p.u[5]=f2h(v1.y); p.u[6]=f2h(v1.z); p.u[7]=f2h(v1.w);
            wregA[kk] = p.v;
        }
#pragma unroll
        for (int kk = 0; kk < 16; ++kk) {
            float4 v0 = *(const float4*)(srcB + kk*32);
            float4 v1 = *(const float4*)(srcB + kk*32 + 4);
            union { unsigned short u[8]; half8 v; } p;
            p.u[0]=f2h(v0.x); p.u[1]=f2h(v0.y); p.u[2]=f2h(v0.z); p.u[3]=f2h(v0.w);
            p.u[4]=f2h(v1.x); p.u[5]=f2h(v1.y); p.u[6]=f2h(v1.z); p.u[7]=f2h(v1.w);
            wregB[kk] = p.v;
        }
    }

    // poll/stage mapping: thread owns 2 x 16B chunks (rows c0row, c0row+8)
    const int c0row = tid >> 6;                // 0..7 (== wv)
    const int colq  = (tid & 63) * 8;          // u16 col of chunk
    const int swz   = (c0row & 7) << 4;
    const int wb0 = c0row*1024 + (((tid & 63)*16) ^ swz);
    const int wb1 = (c0row + 8)*1024 + (((tid & 63)*16) ^ swz);

    const unsigned short* xgdA = xg;
    const unsigned short* xgdB = xg + (size_t)32768 * 2048;
    const float bvA = bias[gate*512 + col];
    const float bvB = bias[2048 + gate*512 + col];
    float carrA[4] = {0.f,0.f,0.f,0.f}, carrB[4] = {0.f,0.f,0.f,0.f};

    auto xga = [&](int t) { return (const ull*)(xgdA + ((size_t)(t*4 + gate)*512 + col)*64 + bh*16 + q*4); };
    auto xgb = [&](int t) { return (const ull*)(xgdB + ((size_t)(t*4 + gate)*512 + col)*64 + bh*16 + q*4); };
    auto ringaddr = [&](int d, int sm1) {
        return (const uint32_t*)(hbuf + ((size_t)((sm1 & 3)*2 + d)*64 + R0 + c0row)*512 + colq);
    };

    auto TAGS = [&](const u32x4& r0, const u32x4& r1, uint32_t ep) -> uint32_t {
        uint32_t bad = 0;
#pragma unroll
        for (int c = 0; c < 4; ++c) bad |= (r0[c] ^ ep) & TM32;
#pragma unroll
        for (int c = 0; c < 4; ++c) bad |= (r1[c] ^ ep) & TM32;
        return bad;
    };
    auto ISSUE = [&](u32x4& r0, u32x4& r1, const uint32_t* a0) {
        r0 = (u32x4){NC, NC, NC, NC};
        r1 = (u32x4){NC, NC, NC, NC};
        asm volatile("global_load_dwordx4 %0, %2, off sc0 sc1\n\t"
                     "global_load_dwordx4 %1, %3, off sc0 sc1"
                     : "+v"(r0), "+v"(r1)
                     : "v"(a0), "v"(a0 + 2048) : "memory");
    };
    // CHECK with counted (loose) vmcnt: early return can only show neutral/stale
    // tags (recheck path); a passed tag check implies the data physically arrived.
    auto CHECKSTAGE = [&](u32x4& r0, u32x4& r1, const uint32_t* a0, uint32_t ep,
                          unsigned short* lbuf, int N) {
        if (N == 2) asm volatile("s_waitcnt vmcnt(2)" : "+v"(r0), "+v"(r1) :: "memory");
        else        asm volatile("s_waitcnt vmcnt(4)" : "+v"(r0), "+v"(r1) :: "memory");
        uint32_t bad = TAGS(r0, r1, ep);
        if (__builtin_expect(bad != 0, 0)) {
            asm volatile("s_waitcnt vmcnt(0)" : "+v"(r0), "+v"(r1) :: "memory");
            bad = TAGS(r0, r1, ep);
            for (int it = 0; bad && it < (1 << 13); ++it) {
                asm volatile("global_load_dwordx4 %0, %2, off sc0 sc1\n\t"
                             "global_load_dwordx4 %1, %3, off sc0 sc1\n\t"
                             "s_waitcnt vmcnt(0)"
                             : "+v"(r0), "+v"(r1)
                             : "v"(a0), "v"(a0 + 2048) : "memory");
                bad = TAGS(r0, r1, ep);
            }
        }
        u32x4 w0 = r0, w1 = r1;
#pragma unroll
        for (int c = 0; c < 4; ++c) { w0[c] &= ~TM32; w1[c] &= ~TM32; }
        *(u32x4*)((char*)lbuf + wb0) = w0;
        *(u32x4*)((char*)lbuf + wb1) = w1;
    };
    auto MFMA = [&](const unsigned short* lbuf, const half8* wreg) -> f32x4 {
        f32x4 acc = (f32x4){0.f,0.f,0.f,0.f};
        const char* hb = (const char*)lbuf + ln*1024;
        const int lswz = (ln & 7) << 4;
#pragma unroll
        for (int kk = 0; kk < 16; ++kk) {
            half8 a = *(const half8*)(hb + ((kk*64 + q*16) ^ lswz));
            acc = __builtin_amdgcn_mfma_f32_16x16x32_f16(a, wreg[kk], acc, 0, 0, 0);
        }
        return acc;
    };
    // pointwise: every lane finishes with its col's h for rows q*4..+3 (4x gate-
    // redundant); gate regroup fully in-register via shfl_xor butterfly.
    auto PW = [&](int d, int s, int t, f32x4 acc, ull xv, float* carr, float bv) {
        unsigned short hs[4];
#pragma unroll
        for (int r = 0; r < 4; ++r) {
            float v  = acc[r] + h2f((unsigned short)(xv >> (16*r))) + bv;
            float o1 = __shfl_xor(v, 1);
            float e  = (gate & 1) ? o1 : v;    // gate bit0=0 of the pair
            float od = (gate & 1) ? v  : o1;   // gate bit0=1
            float e2 = __shfl_xor(e, 2);
            float od2= __shfl_xor(od, 2);
            float gi = (gate & 2) ? e2 : e;    // gate 0 (i)
            float gg = (gate & 2) ? e  : e2;   // gate 2 (g)
            float gf = (gate & 2) ? od2: od;   // gate 1 (f)
            float go = (gate & 2) ? od : od2;  // gate 3 (o)
            float si = 1.f / (1.f + __expf(-gi));
            float sf = 1.f / (1.f + __expf(-gf));
            float so = 1.f / (1.f + __expf(-go));
            float tg = 2.f / (1.f + __expf(-2.f*gg)) - 1.f;
            float c  = sf * carr[r] + si * tg;
            carr[r] = c;
            float th = 2.f / (1.f + __expf(-2.f*c)) - 1.f;
            hs[r] = f2h(so * th);
        }
        // intra-wave repack: gate-0 lanes write [row][4 cols]; lanes 0..15 store rows
        if (gate == 0) {
#pragma unroll
            for (int r = 0; r < 4; ++r) htile[wv*64 + (q*4 + r)*4 + lc] = hs[r];
        }
        if (lane < 16) {
            ull hv64 = *(const ull*)(htile + wv*64 + lane*4);
            const int row  = R0 + lane;
            const int colb = C0 + wv*4;
            const ull wpat = ((s >> 2) & 1) ? pat1 : pat0;
            AS((ull*)(hbuf + ((size_t)((s & 3)*2 + d)*64 + row)*512 + colb), hv64 | wpat);
            if (layer == 0) {
                __builtin_nontemporal_store(hv64,
                    (ull*)(outh + ((size_t)t*64 + row)*1024 + d*512 + colb));
            } else {
                union { ull u; unsigned short us[4]; } pu; pu.u = hv64;
                f32x4 o; o[0]=h2f(pu.us[0]); o[1]=h2f(pu.us[1]);
                o[2]=h2f(pu.us[2]); o[3]=h2f(pu.us[3]);
                __builtin_nontemporal_store(o,
                    (f32x4*)(outf + ((size_t)t*64 + row)*1024 + d*512 + colb));
            }
        }
    };

    u32x4 rA0, rA1, rB0, rB1;
    ull xvA, xvB, xvAn, xvBn;

    // ---- prologue: s=0 both chains (acc = 0), then issue A(1) ----
    {
        f32x4 z = (f32x4){0.f,0.f,0.f,0.f};
        xvA = __builtin_nontemporal_load(xga(0));
        xvB = __builtin_nontemporal_load(xgb(511));
        PW(0, 0, 0,   z, xvA, carrA, bvA);
        PW(1, 0, 511, z, xvB, carrB, bvB);
        xvA = __builtin_nontemporal_load(xga(1));
        xvB = __builtin_nontemporal_load(xgb(510));
        ISSUE(rA0, rA1, ringaddr(0, 0));
    }

    // ---- main loop: 2 barriers/iter; LDS double-buffer proof: a buffer parity
    // is rewritten 2 steps later, and >=3 barriers separate the last reader from
    // the next writer (waves can never be that far apart). ----
#pragma unroll 1
    for (int s = 1; s < 512; ++s) {
        const int tA = s, tB = 511 - s;
        unsigned short* bufA = h_lds + ((s & 1)) * 8192;
        unsigned short* bufB = h_lds + (2 + (s & 1)) * 8192;
        const uint32_t ep = (((s - 1) >> 2) & 1) ? ep1 : ep0;

        // chain A: check loads issued last iter (vmcnt(2): 2 pwB stores after it)
        CHECKSTAGE(rA0, rA1, ringaddr(0, s - 1), ep, bufA, 2);
        ISSUE(rB0, rB1, ringaddr(1, s - 1));      // B's latency hides under mfmaA+pwA
        __syncthreads();                          // bar1: bufA staged
        f32x4 accA = MFMA(bufA, wregA);
        if (s < 511) {                            // xg prefetch for s+1 (2 vm loads)
            xvAn = __builtin_nontemporal_load(xga(s + 1));
            xvBn = __builtin_nontemporal_load(xgb(510 - s));
        }
        PW(0, s, tA, accA, xvA, carrA, bvA);      // + 2 vm stores

        // chain B: check (vmcnt(4): 2 xg loads + 2 pwA stores after its issue)
        CHECKSTAGE(rB0, rB1, ringaddr(1, s - 1), ep, bufB, 4);
        ISSUE(rA0, rA1, ringaddr(0, s));          // A(s+1); hides under mfmaB+pwB
        __syncthreads();                          // bar2: bufB staged
        f32x4 accB = MFMA(bufB, wregB);
        PW(1, s, tB, accB, xvB, carrB, bvB);
        xvA = xvAn; xvB = xvBn;
    }
}

extern "C" void kernel_launch(void* const* d_in, const int* in_sizes, int n_in,
                              void* d_out, int out_size, void* d_ws, size_t ws_size,
                              hipStream_t stream)
{
    (void)in_sizes; (void)n_in; (void)out_size; (void)ws_size;
    const float* x       = (const float*)d_in[0];
    const float* w_ih0_f = (const float*)d_in[1];
    const float* w_hh0_f = (const float*)d_in[2];
    const float* b_ih0_f = (const float*)d_in[3];
    const float* b_hh0_f = (const float*)d_in[4];
    const float* w_ih0_b = (const float*)d_in[5];
    const float* w_hh0_b = (const float*)d_in[6];
    const float* b_ih0_b = (const float*)d_in[7];
    const float* b_hh0_b = (const float*)d_in[8];
    const float* w_ih1_f = (const float*)d_in[9];
    const float* w_hh1_f = (const float*)d_in[10];
    const float* b_ih1_f = (const float*)d_in[11];
    const float* b_hh1_f = (const float*)d_in[12];
    const float* w_ih1_b = (const float*)d_in[13];
    const float* w_hh1_b = (const float*)d_in[14];
    const float* b_ih1_b = (const float*)d_in[15];
    const float* b_hh1_b = (const float*)d_in[16];

    // workspace layout (bytes): xg 256MB | wih_h 12MB | bias 32KB | hbuf ring 512KB
    char* ws = (char*)d_ws;
    unsigned short* xg    = (unsigned short*)(ws + 0);
    unsigned short* wihh  = (unsigned short*)(ws + 268435456L);
    float*          bias  = (float*)         (ws + 281018368L);
    unsigned short* hbuf  = (unsigned short*)(ws + 281051136L);

    // scratch stashed inside d_out (consumed before final output is written):
    unsigned short* in1 = (unsigned short*)d_out;                      // 67MB fp16 [T][64][1024]
    unsigned short* xh  = (unsigned short*)((char*)d_out + 67108864L); // 33.5MB fp16 x
    float* outf = (float*)d_out;

    prep_kernel<<<dim3(1024), dim3(256), 0, stream>>>(
        x, w_ih0_f, w_ih0_b, w_ih1_f, w_ih1_b,
        b_ih0_f, b_hh0_f, b_ih0_b, b_hh0_b,
        b_ih1_f, b_hh1_f, b_ih1_b, b_hh1_b,
        xh, wihh, bias, (uint32_t*)hbuf);

    // layer 0 (tag alphabet {0000,1111})
    gemm_xg<<<dim3(16, 256, 2), dim3(256), 0, stream>>>(
        xh, wihh, wihh + 1048576, xg, 512);
    rec_kernel<<<dim3(64), dim3(512), 0, stream>>>(
        xg, w_hh0_f, w_hh0_b, bias, hbuf, in1, (float*)nullptr, 0);

    // layer 1 (tag alphabet {1010,0101} — orthogonal to L0 residue and to init)
    gemm_xg<<<dim3(16, 256, 2), dim3(256), 0, stream>>>(
        in1, wihh + 2097152, wihh + 4194304, xg, 1024);
    rec_kernel<<<dim3(64), dim3(512), 0, stream>>>(
        xg, w_hh1_f, w_hh1_b, bias + 4096, hbuf,
        (unsigned short*)nullptr, outf, 1);
}

// Round 8
// 5103.075 us; speedup vs baseline: 1.4027x; 1.4027x over previous
//
#include <hip/hip_runtime.h>
#include <hip/hip_bf16.h>
#include <stdint.h>

// LSTM bidirectional 2-layer, T=512 B=64 D=H=512.
// prep(cast+bias+ring-init) -> gemm_xg(L0) -> rec(L0) -> gemm_xg(L1) -> rec(L1).
// R7: single-hop sync on a COMPACT 512KB ring with per-u16 tag-in-data
//   (h in [-1,1] => fp16 bit14 always 0). Orthogonal per-layer tag alphabets:
//   L0 {0000,1111}, L1 {1010,0101}, ring init = neutral 0011 (matches nothing).
// R9: dual-chain (fwd+bwd) per WG, 64 WGs x 512 thr. (2152us/rec baseline)
// R10 post-mortem: reg-weights + lambdas + all-wave PW spilled (WRITE 483MB) ->
//   reverted. R9's weights were auto-AGPR'd (VGPR=128, no spill) - keep R9 form.
// R11: (a) split-issue polls: A+B ring loads issued together at iter top; A
//   checked with counted vmcnt(2) (B stays in flight under mfmaA+pwA); B checked
//   with wave-uniform counted vmcnt(4/5 on g0 waves: 2 xg loads + 2/3 stores
//   after B; vmcnt(0) on others). Store-acks never drained on the hot path.
//   Only rB quads (+8 VGPR) live across the A-phase.
//   (b) XCD swap: cg = bx&15, bh = bx>>4 -> the 4 bh-WGs of a cg share an XCD
//   (bx%8 = cg%8), so each 128B xg line (split 4 ways by bh) is HBM-fetched
//   once per XCD, not 4x (R9 FETCH 623MB vs 268MB compulsory).
// R5 carry-over: xg stores/loads non-temporal.

typedef __attribute__((ext_vector_type(8))) _Float16 half8;
typedef __attribute__((ext_vector_type(4))) float f32x4;
typedef __attribute__((ext_vector_type(4))) uint32_t u32x4;
typedef unsigned long long ull;

#define AS(p, v) __hip_atomic_store((p), (v), __ATOMIC_RELAXED, __HIP_MEMORY_SCOPE_AGENT)

#define TAGMASK 0x4000400040004000ULL   // bit14 of halves 0..3
#define TM32    0x40004000u
#define PAT_L1A 0x0000400000004000ULL   // halves 0,2  (L1 parity 0)
#define PAT_L1B 0x4000000040000000ULL   // halves 1,3  (L1 parity 1)
// neutral ring-init pattern: halves 0,1 tagged -> matches no layer expectation
#define PAT_INIT_LO 0x40004000u
#define PAT_INIT_HI 0x00000000u

__device__ __forceinline__ unsigned short f2h(float f) {
    union { _Float16 h; unsigned short u; } c; c.h = (_Float16)f; return c.u;
}
__device__ __forceinline__ float h2f(unsigned short u) {
    union { _Float16 h; unsigned short u; } c; c.u = u; return (float)c.h;
}

// ---------------- prep: casts, bias sums, ring init (neutral pattern) ----------------
__global__ __launch_bounds__(256) void prep_kernel(
    const float* __restrict__ x,
    const float* __restrict__ w0f, const float* __restrict__ w0b,
    const float* __restrict__ w1f, const float* __restrict__ w1b,
    const float* __restrict__ bi0f, const float* __restrict__ bh0f,
    const float* __restrict__ bi0b, const float* __restrict__ bh0b,
    const float* __restrict__ bi1f, const float* __restrict__ bh1f,
    const float* __restrict__ bi1b, const float* __restrict__ bh1b,
    unsigned short* __restrict__ xh,
    unsigned short* __restrict__ wihh,
    float* __restrict__ bias,
    uint32_t* __restrict__ hbufi)          // ring init: 512KB neutral pattern
{
    const long total = 5801984L;   // units of 16B quads
    long stride = (long)gridDim.x * blockDim.x;
    for (long i = (long)blockIdx.x * blockDim.x + threadIdx.x; i < total; i += stride) {
        if (i < 4194304L) {                       // x: fp32 -> fp16 (16.78M elems)
            float4 v = ((const float4*)x)[i];
            ushort4 o; o.x=f2h(v.x); o.y=f2h(v.y); o.z=f2h(v.z); o.w=f2h(v.w);
            ((ushort4*)xh)[i] = o;
        } else if (i < 5767168L) {                // w_ih casts: [w0f][w0b][w1f][w1b]
            long j = i - 4194304L;
            const float* src; long sq;
            if (j < 262144L)       { src = w0f; sq = j;            }
            else if (j < 524288L)  { src = w0b; sq = j - 262144L;  }
            else if (j < 1048576L) { src = w1f; sq = j - 524288L;  }
            else                   { src = w1b; sq = j - 1048576L; }
            float4 v = ((const float4*)src)[sq];
            ushort4 o; o.x=f2h(v.x); o.y=f2h(v.y); o.z=f2h(v.z); o.w=f2h(v.w);
            ((ushort4*)wihh)[j] = o;
        } else if (i < 5769216L) {                // bias sums: b_ih + b_hh, 4 x 2048 fp32
            long j = i - 5767168L;                // 0..2047 quads
            int ld = (int)(j >> 9);
            long cq = j & 511L;
            const float* bi = ld==0?bi0f: ld==1?bi0b: ld==2?bi1f:bi1b;
            const float* bh = ld==0?bh0f: ld==1?bh0b: ld==2?bh1f:bh1b;
            float4 a = ((const float4*)bi)[cq];
            float4 b = ((const float4*)bh)[cq];
            float4 o; o.x=a.x+b.x; o.y=a.y+b.y; o.z=a.z+b.z; o.w=a.w+b.w;
            ((float4*)bias)[ld*512 + cq] = o;
        } else {                                  // ring init: 32768 quads = 512KB
            long j = i - 5769216L;
            uint4 p; p.x=PAT_INIT_LO; p.y=PAT_INIT_HI; p.z=PAT_INIT_LO; p.w=PAT_INIT_HI;
            ((uint4*)hbufi)[j] = p;
        }
    }
}

// ---------------- xg GEMM: xg = A @ W^T, fp16 out, TRANSPOSED layout ----------------
__global__ __launch_bounds__(256) void gemm_xg(
    const unsigned short* __restrict__ A,
    const unsigned short* __restrict__ Wf,
    const unsigned short* __restrict__ Wb,
    unsigned short* __restrict__ xg,
    int Din)
{
    __shared__ __align__(16) unsigned short As[4096];   // 128 rows x 32 k, fp16
    __shared__ __align__(16) unsigned short Bs[4096];
    const int dir = blockIdx.z;
    const unsigned short* W = dir ? Wb : Wf;
    unsigned short* out = xg + (size_t)dir * 32768 * 2048;
    const int bn = blockIdx.x, bm = blockIdx.y;
    const int tid = threadIdx.x;
    const int wave = tid >> 6, lane = tid & 63;
    const int q = lane >> 4, ln = lane & 15;
    const int wm = wave >> 1, wn = wave & 1;

    f32x4 acc[4][4];
#pragma unroll
    for (int a = 0; a < 4; ++a)
#pragma unroll
        for (int b = 0; b < 4; ++b) acc[a][b] = (f32x4){0.f, 0.f, 0.f, 0.f};

    const int kiter = Din >> 5;
    for (int kb = 0; kb < kiter; ++kb) {
        __syncthreads();
#pragma unroll
        for (int i = 0; i < 2; ++i) {
            int off = i*4096 + wave*1024 + lane*16;   // byte offset in 8KB tile
            int row = off >> 6;
            int kel = (off & 63) >> 1;
            const unsigned short* sa = A + (size_t)(bm*128 + row)*Din + kb*32 + kel;
            const unsigned short* sb = W + (size_t)(bn*128 + row)*Din + kb*32 + kel;
            __builtin_amdgcn_global_load_lds(
                (const __attribute__((address_space(1))) uint32_t*)sa,
                (__attribute__((address_space(3))) uint32_t*)((char*)As + i*4096 + wave*1024),
                16, 0, 0);
            __builtin_amdgcn_global_load_lds(
                (const __attribute__((address_space(1))) uint32_t*)sb,
                (__attribute__((address_space(3))) uint32_t*)((char*)Bs + i*4096 + wave*1024),
                16, 0, 0);
        }
        __syncthreads();
        half8 af[4], bf[4];
#pragma unroll
        for (int mt = 0; mt < 4; ++mt)
            af[mt] = *(const half8*)((const char*)As + (wm*64 + mt*16 + ln)*64 + q*16);
#pragma unroll
        for (int nt = 0; nt < 4; ++nt)
            bf[nt] = *(const half8*)((const char*)Bs + (wn*64 + nt*16 + ln)*64 + q*16);
#pragma unroll
        for (int mt = 0; mt < 4; ++mt)
#pragma unroll
            for (int nt = 0; nt < 4; ++nt)
                acc[mt][nt] = __builtin_amdgcn_mfma_f32_16x16x32_f16(af[mt], bf[nt], acc[mt][nt], 0, 0, 0);
    }
    const int tt = bm*2 + wm;
#pragma unroll
    for (int mt = 0; mt < 4; ++mt)
#pragma unroll
        for (int nt = 0; nt < 4; ++nt) {
            int col = bn*128 + wn*64 + nt*16 + ln;
            int gate = col >> 9, colg = col & 511;
            union { unsigned short u[4]; ull v; } p;
#pragma unroll
            for (int r = 0; r < 4; ++r) p.u[r] = f2h(acc[mt][nt][r]);
            __builtin_nontemporal_store(p.v,
                (ull*)(out + (((size_t)tt*4 + gate)*512 + colg)*64 + mt*16 + q*4));
        }
}

// ---------------- recurrent kernel: one layer, BOTH directions per WG ----------------
// 64 WGs x 512 threads (8 waves). WG = (bh batch/16, cg: 32 h-cols), both dirs.
struct RecCtx {
    const unsigned short* hbuf_c;
    unsigned short* hbuf;
    unsigned short* outh;
    float* outf;
    int layer, R0, C0, tid, wv, lane, g, wc, ln, q;
    int c0row, colq, wb0, wb1;
    uint32_t ep0, ep1;
    ull pat0, pat1;
};

__device__ __forceinline__ uint32_t tagbad(const u32x4& r0, const u32x4& r1, uint32_t ep)
{
    uint32_t bad = 0;
#pragma unroll
    for (int c = 0; c < 4; ++c) bad |= (r0[c] ^ ep) & TM32;
#pragma unroll
    for (int c = 0; c < 4; ++c) bad |= (r1[c] ^ ep) & TM32;
    return bad;
}

// slow path: drain + reload until tags match
__device__ __forceinline__ void retry_poll(u32x4& r0, u32x4& r1,
    const uint32_t* a0, uint32_t ep)
{
    asm volatile("s_waitcnt vmcnt(0)" : "+v"(r0), "+v"(r1) :: "memory");
    uint32_t bad = tagbad(r0, r1, ep);
    for (int it = 0; bad && it < (1 << 13); ++it) {
        asm volatile("global_load_dwordx4 %0, %2, off sc0 sc1\n\t"
                     "global_load_dwordx4 %1, %3, off sc0 sc1\n\t"
                     "s_waitcnt vmcnt(0)"
                     : "+v"(r0), "+v"(r1)
                     : "v"(a0), "v"(a0 + 2048) : "memory");
        bad = tagbad(r0, r1, ep);
    }
}

__device__ __forceinline__ void stage_lds(const RecCtx& cx, u32x4 r0, u32x4 r1,
                                          unsigned short* lbuf)
{
#pragma unroll
    for (int c = 0; c < 4; ++c) { r0[c] &= ~TM32; r1[c] &= ~TM32; }
    *(u32x4*)((char*)lbuf + cx.wb0) = r0;
    *(u32x4*)((char*)lbuf + cx.wb1) = r1;
}

__device__ __forceinline__ void mfma_phase(const RecCtx& cx,
    const unsigned short* lbuf, const half8* wreg, float* achb)
{
    f32x4 acc = (f32x4){0.f, 0.f, 0.f, 0.f};
    const char* hbase = (const char*)lbuf + cx.ln*1024;
    const int lswz = (cx.ln & 7) << 4;
#pragma unroll
    for (int kk = 0; kk < 16; ++kk) {
        half8 a = *(const half8*)(hbase + ((kk*64 + cx.q*16) ^ lswz));
        acc = __builtin_amdgcn_mfma_f32_16x16x32_f16(a, wreg[kk], acc, 0, 0, 0);
    }
    *(f32x4*)&achb[(cx.wv*16 + cx.ln)*20 + cx.q*4] = acc;
}

__device__ __forceinline__ void pointwise(const RecCtx& cx, int d, int s, int t,
    const ull* xv, float* carr, const float* achb, unsigned short* htb,
    float bv0, float bv1, float bv2, float bv3)
{
    f32x4 a0 = *(const f32x4*)&achb[((0*2 + cx.wc)*16 + cx.ln)*20 + cx.q*4];
    f32x4 a1 = *(const f32x4*)&achb[((1*2 + cx.wc)*16 + cx.ln)*20 + cx.q*4];
    f32x4 a2 = *(const f32x4*)&achb[((2*2 + cx.wc)*16 + cx.ln)*20 + cx.q*4];
    f32x4 a3 = *(const f32x4*)&achb[((3*2 + cx.wc)*16 + cx.ln)*20 + cx.q*4];
    unsigned short hs[4];
#pragma unroll
    for (int r = 0; r < 4; ++r) {
        float gi = a0[r] + h2f((unsigned short)(xv[0] >> (16*r))) + bv0;
        float gf = a1[r] + h2f((unsigned short)(xv[1] >> (16*r))) + bv1;
        float gg = a2[r] + h2f((unsigned short)(xv[2] >> (16*r))) + bv2;
        float go = a3[r] + h2f((unsigned short)(xv[3] >> (16*r))) + bv3;
        float si = 1.f / (1.f + __expf(-gi));
        float sf = 1.f / (1.f + __expf(-gf));
        float so = 1.f / (1.f + __expf(-go));
        float tg = 2.f / (1.f + __expf(-2.f*gg)) - 1.f;
        float c  = sf * carr[r] + si * tg;
        carr[r] = c;
        float th = 2.f / (1.f + __expf(-2.f*c)) - 1.f;
        hs[r] = f2h(so * th);
    }
    // repack 16x16 tile via per-wave LDS scratch (intra-wave, no barrier)
    unsigned short* ht = htb + cx.wc*256;
#pragma unroll
    for (int r = 0; r < 4; ++r) ht[(cx.q*4 + r)*16 + cx.ln] = hs[r];
    ull hv64 = *(const ull*)(ht + (cx.lane >> 2)*16 + (cx.lane & 3)*4);
    const int row  = cx.R0 + (cx.lane >> 2);
    const int colw = cx.C0 + cx.wc*16 + (cx.lane & 3)*4;

    // ring store FIRST (critical path): tagged, single 8B relaxed atomic.
    const int slot_w = s & 3;
    const ull wpat = ((s >> 2) & 1) ? cx.pat1 : cx.pat0;
    AS((ull*)(cx.hbuf + ((size_t)(slot_w*2 + d)*64 + row)*512 + colw), hv64 | wpat);

    // layer output: plain non-temporal store, off the critical path.
    if (cx.layer == 0) {
        __builtin_nontemporal_store(hv64,
            (ull*)(cx.outh + ((size_t)t*64 + row)*1024 + d*512 + colw));
    } else {
        union { ull u; unsigned short us[4]; } pu; pu.u = hv64;
        union { ull u; float f[2]; } o0, o1;
        o0.f[0] = h2f(pu.us[0]); o0.f[1] = h2f(pu.us[1]);
        o1.f[0] = h2f(pu.us[2]); o1.f[1] = h2f(pu.us[3]);
        ull* dst = (ull*)(cx.outf + ((size_t)t*64 + row)*1024 + d*512 + colw);
        __builtin_nontemporal_store(o0.u, dst);
        __builtin_nontemporal_store(o1.u, dst + 1);
    }
}

__global__ __launch_bounds__(512, 2) void rec_kernel(
    const unsigned short* __restrict__ xg,    // [dir][t][gate][hcol][brow] fp16, bias-free
    const float* __restrict__ whhf,           // [2048][512] fp32
    const float* __restrict__ whhb,
    const float* __restrict__ bias,           // [2 dir][2048] fp32 (b_ih+b_hh)
    unsigned short* __restrict__ hbuf,        // ring [4 slot][2 dir][64][512] fp16, tagged
    unsigned short* __restrict__ outh,        // layer0: in1 [T][64][1024] fp16
    float* __restrict__ outf,                 // layer1: d_out fp32 [T][64][1024]
    const int layer)
{
    __shared__ __align__(16) unsigned short h_lds[2][8192];   // 32KB: [chain][16r][512c] swz
    __shared__ __align__(16) float accbuf[2][2560];           // 20KB: [chain][wv*16+ln][20] pad
    __shared__ __align__(16) unsigned short htile[2][512];    // 2KB repack scratch

    const int bx = blockIdx.x;                 // 64 WGs
    RecCtx cx;
    cx.hbuf_c = hbuf; cx.hbuf = hbuf; cx.outh = outh; cx.outf = outf;
    cx.layer = layer;
    // R11 XCD swap: 4 bh-WGs of a cg share XCD (bx%8 == cg%8)
    const int cg = bx & 15, bh = bx >> 4;
    cx.R0 = bh * 16; cx.C0 = cg * 32;
    cx.tid = threadIdx.x;
    cx.wv = cx.tid >> 6; cx.lane = cx.tid & 63;
    cx.g = cx.wv >> 1; cx.wc = cx.wv & 1;
    cx.ln = cx.lane & 15; cx.q = cx.lane >> 4;
    cx.pat0 = layer ? PAT_L1A : 0ULL;
    cx.pat1 = layer ? PAT_L1B : TAGMASK;
    cx.ep0 = (uint32_t)(cx.pat0 & 0xffffffffULL);
    cx.ep1 = (uint32_t)(cx.pat1 & 0xffffffffULL);
    // conflict-free staging map: thread owns chunks tid and tid+512 (16B each)
    cx.c0row = cx.tid >> 6;                    // rows 0..7 (+8 for second chunk)
    cx.colq  = (cx.tid & 63) * 8;              // u16 col of chunk
    cx.wb0 = cx.c0row*1024 + (((cx.tid & 63)*16) ^ ((cx.c0row & 7) << 4));
    cx.wb1 = (cx.c0row + 8)*1024 + (((cx.tid & 63)*16) ^ ((cx.c0row & 7) << 4));

    // ---- W_hh -> registers, BOTH dirs (static names; compiler AGPR-promotes) ----
    half8 wregA[16], wregB[16];
    {
        const int wrow = cx.g*512 + cx.C0 + cx.wc*16 + cx.ln;
        const float* srcA = whhf + (size_t)wrow * 512 + cx.q*8;
        const float* srcB = whhb + (size_t)wrow * 512 + cx.q*8;
#pragma unroll
        for (int kk = 0; kk < 16; ++kk) {
            float4 v0 = *(const float4*)(srcA + kk*32);
            float4 v1 = *(const float4*)(srcA + kk*32 + 4);
            union { unsigned short u[8]; half8 v; } p;
            p.u[0]=f2h(v0.x); p.u[1]=f2h(v0.y); p.u[2]=f2h(v0.z); p.u[3]=f2h(v0.w);
            p.u[4]=f2h(v1.x); p.u[5]=f2h(v1.y); p.u[6]=f2h(v1.z); p.u[7]=f2h(v1.w);
            wregA[kk] = p.v;
        }
#pragma unroll
        for (int kk = 0; kk < 16; ++kk) {
            float4 v0 = *(const float4*)(srcB + kk*32);
            float4 v1 = *(const float4*)(srcB + kk*32 + 4);
            union { unsigned short u[8]; half8 v; } p;
            p.u[0]=f2h(v0.x); p.u[1]=f2h(v0.y); p.u[2]=f2h(v0.z); p.u[3]=f2h(v0.w);
            p.u[4]=f2h(v1.x); p.u[5]=f2h(v1.y); p.u[6]=f2h(v1.z); p.u[7]=f2h(v1.w);
            wregB[kk] = p.v;
        }
    }

    const unsigned short* xgdA = xg;
    const unsigned short* xgdB = xg + (size_t)32768 * 2048;
    const int myc = cx.C0 + cx.wc*16 + cx.ln;
    float bvA0 = bias[0*512 + myc],        bvA1 = bias[1*512 + myc];
    float bvA2 = bias[2*512 + myc],        bvA3 = bias[3*512 + myc];
    float bvB0 = bias[2048 + 0*512 + myc], bvB1 = bias[2048 + 1*512 + myc];
    float bvB2 = bias[2048 + 2*512 + myc], bvB3 = bias[2048 + 3*512 + myc];
    float carrA[4] = {0.f,0.f,0.f,0.f}, carrB[4] = {0.f,0.f,0.f,0.f};
    ull xvA[4] = {0,0,0,0}, xvB[4] = {0,0,0,0};
    ull xvAn[4] = {0,0,0,0}, xvBn[4] = {0,0,0,0};

    const size_t xoff = (size_t)bh*16 + cx.q*4;   // brow base within xg row

    // ---- prologue: s=0 both chains (acc = 0) ----
    {
        f32x4 z = (f32x4){0.f,0.f,0.f,0.f};
        *(f32x4*)&accbuf[0][(cx.wv*16 + cx.ln)*20 + cx.q*4] = z;
        *(f32x4*)&accbuf[1][(cx.wv*16 + cx.ln)*20 + cx.q*4] = z;
        __syncthreads();
        if (cx.g == 0) {
#pragma unroll
            for (int k = 0; k < 4; ++k) {
                xvA[k] = __builtin_nontemporal_load(
                    (const ull*)(xgdA + ((size_t)(0*4 + k)*512 + myc)*64 + xoff));
                xvB[k] = __builtin_nontemporal_load(
                    (const ull*)(xgdB + ((size_t)(511*4 + k)*512 + myc)*64 + xoff));
            }
            pointwise(cx, 0, 0, 0,   xvA, carrA, accbuf[0], htile[0], bvA0,bvA1,bvA2,bvA3);
            pointwise(cx, 1, 0, 511, xvB, carrB, accbuf[1], htile[1], bvB0,bvB1,bvB2,bvB3);
#pragma unroll
            for (int k = 0; k < 4; ++k) {
                xvA[k] = __builtin_nontemporal_load(
                    (const ull*)(xgdA + ((size_t)(1*4 + k)*512 + myc)*64 + xoff));
                xvB[k] = __builtin_nontemporal_load(
                    (const ull*)(xgdB + ((size_t)(510*4 + k)*512 + myc)*64 + xoff));
            }
        }
    }

    // ---- main loop: split-issue A+B at top; counted waits keep B in flight
    // under mfmaA+pwA. 4 barriers/iter (as R9). ----
#pragma unroll 1
    for (int s = 1; s < 512; ++s) {
        const int tA = s, tB = 511 - s;
        const int slot_r = (s - 1) & 3;
        const uint32_t ep = (((s - 1) >> 2) & 1) ? cx.ep1 : cx.ep0;
        const uint32_t* pa = (const uint32_t*)(cx.hbuf_c
            + ((size_t)(slot_r*2 + 0)*64 + cx.R0 + cx.c0row)*512 + cx.colq);
        const uint32_t* pb = (const uint32_t*)(cx.hbuf_c
            + ((size_t)(slot_r*2 + 1)*64 + cx.R0 + cx.c0row)*512 + cx.colq);

        u32x4 rA0, rA1, rB0, rB1;
        asm volatile("global_load_dwordx4 %0, %4, off sc0 sc1\n\t"
                     "global_load_dwordx4 %1, %5, off sc0 sc1\n\t"
                     "global_load_dwordx4 %2, %6, off sc0 sc1\n\t"
                     "global_load_dwordx4 %3, %7, off sc0 sc1"
                     : "=&v"(rA0), "=&v"(rA1), "=&v"(rB0), "=&v"(rB1)
                     : "v"(pa), "v"(pa + 2048), "v"(pb), "v"(pb + 2048)
                     : "memory");
        // wait A only (2 newest = B stay outstanding)
        asm volatile("s_waitcnt vmcnt(2)" : "+v"(rA0), "+v"(rA1) :: "memory");
        if (__builtin_expect(tagbad(rA0, rA1, ep) != 0, 0))
            retry_poll(rA0, rA1, pa, ep);
        stage_lds(cx, rA0, rA1, h_lds[0]);
        __syncthreads();                                     // bar1: bufA staged

        if (cx.g == 0) {                                     // xg prefetch for s+1
#pragma unroll
            for (int k = 0; k < 4; ++k) {
                xvAn[k] = __builtin_nontemporal_load(
                    (const ull*)(xgdA + ((size_t)((s+1)*4 + k)*512 + myc)*64 + xoff));
                xvBn[k] = __builtin_nontemporal_load(
                    (const ull*)(xgdB + ((size_t)((510-s)*4 + k)*512 + myc)*64 + xoff));
            }
        }
        mfma_phase(cx, h_lds[0], wregA, accbuf[0]);
        __syncthreads();                                     // bar2
        if (cx.g == 0)
            pointwise(cx, 0, s, tA, xvA, carrA, accbuf[0], htile[0], bvA0,bvA1,bvA2,bvA3);

        // wait B with wave-uniform counted vmcnt (never drains own store-acks):
        // g0 waves issued after B: 8 xv loads? no - per-thread: 8 loads are 8 instrs
        // only on g0 threads? xv prefetch = 8 loads per g0 thread; plus pw stores.
        // Per g0-WAVE instruction count after B: 8 xv + ring(1) + out(1 or 2).
        if (cx.g == 0) {
            if (layer == 0) asm volatile("s_waitcnt vmcnt(10)" : "+v"(rB0), "+v"(rB1) :: "memory");
            else            asm volatile("s_waitcnt vmcnt(11)" : "+v"(rB0), "+v"(rB1) :: "memory");
        } else {
            asm volatile("s_waitcnt vmcnt(0)"  : "+v"(rB0), "+v"(rB1) :: "memory");
        }
        if (__builtin_expect(tagbad(rB0, rB1, ep) != 0, 0))
            retry_poll(rB0, rB1, pb, ep);
        stage_lds(cx, rB0, rB1, h_lds[1]);
        __syncthreads();                                     // bar3: bufB staged
        mfma_phase(cx, h_lds[1], wregB, accbuf[1]);
        __syncthreads();                                     // bar4
        if (cx.g == 0) {
            pointwise(cx, 1, s, tB, xvB, carrB, accbuf[1], htile[1], bvB0,bvB1,bvB2,bvB3);
#pragma unroll
            for (int k = 0; k < 4; ++k) { xvA[k] = xvAn[k]; xvB[k] = xvBn[k]; }
        }
    }
}

extern "C" void kernel_launch(void* const* d_in, const int* in_sizes, int n_in,
                              void* d_out, int out_size, void* d_ws, size_t ws_size,
                              hipStream_t stream)
{
    (void)in_sizes; (void)n_in; (void)out_size; (void)ws_size;
    const float* x       = (const float*)d_in[0];
    const float* w_ih0_f = (const float*)d_in[1];
    const float* w_hh0_f = (const float*)d_in[2];
    const float* b_ih0_f = (const float*)d_in[3];
    const float* b_hh0_f = (const float*)d_in[4];
    const float* w_ih0_b = (const float*)d_in[5];
    const float* w_hh0_b = (const float*)d_in[6];
    const float* b_ih0_b = (const float*)d_in[7];
    const float* b_hh0_b = (const float*)d_in[8];
    const float* w_ih1_f = (const float*)d_in[9];
    const float* w_hh1_f = (const float*)d_in[10];
    const float* b_ih1_f = (const float*)d_in[11];
    const float* b_hh1_f = (const float*)d_in[12];
    const float* w_ih1_b = (const float*)d_in[13];
    const float* w_hh1_b = (const float*)d_in[14];
    const float* b_ih1_b = (const float*)d_in[15];
    const float* b_hh1_b = (const float*)d_in[16];

    // workspace layout (bytes): xg 256MB | wih_h 12MB | bias 32KB | hbuf ring 512KB
    char* ws = (char*)d_ws;
    unsigned short* xg    = (unsigned short*)(ws + 0);
    unsigned short* wihh  = (unsigned short*)(ws + 268435456L);
    float*          bias  = (float*)         (ws + 281018368L);
    unsigned short* hbuf  = (unsigned short*)(ws + 281051136L);

    // scratch stashed inside d_out (consumed before final output is written):
    unsigned short* in1 = (unsigned short*)d_out;                      // 67MB fp16 [T][64][1024]
    unsigned short* xh  = (unsigned short*)((char*)d_out + 67108864L); // 33.5MB fp16 x
    float* outf = (float*)d_out;

    prep_kernel<<<dim3(1024), dim3(256), 0, stream>>>(
        x, w_ih0_f, w_ih0_b, w_ih1_f, w_ih1_b,
        b_ih0_f, b_hh0_f, b_ih0_b, b_hh0_b,
        b_ih1_f, b_hh1_f, b_ih1_b, b_hh1_b,
        xh, wihh, bias, (uint32_t*)hbuf);

    // layer 0 (tag alphabet {0000,1111})
    gemm_xg<<<dim3(16, 256, 2), dim3(256), 0, stream>>>(
        xh, wihh, wihh + 1048576, xg, 512);
    rec_kernel<<<dim3(64), dim3(512), 0, stream>>>(
        xg, w_hh0_f, w_hh0_b, bias, hbuf, in1, (float*)nullptr, 0);

    // layer 1 (tag alphabet {1010,0101} — orthogonal to L0 residue and to init)
    gemm_xg<<<dim3(16, 256, 2), dim3(256), 0, stream>>>(
        in1, wihh + 2097152, wihh + 4194304, xg, 1024);
    rec_kernel<<<dim3(64), dim3(512), 0, stream>>>(
        xg, w_hh1_f, w_hh1_b, bias + 4096, hbuf,
        (unsigned short*)nullptr, outf, 1);
}